// Round 1
// baseline (6782.312 us; speedup 1.0000x reference)
//
#include <hip/hip_runtime.h>
#include <cmath>

// Problem constants
#define S_LEN 2048
#define HID 4096
#define NHEAD 32
#define Q_LORA 1536
#define KV_LORA 512
#define NOPE 128
#define ROPE_D 64
#define VDIM 128
#define QK_DIM 192       // NOPE + ROPE
#define FUSED_N 2112     // Q_LORA + KV_LORA + ROPE

// ---------------------------------------------------------------------------
// Generic tiled fp32 GEMM:  C(M,N) = A(M,K; lda) * B(N,K; ldb=K)^T
// BM=BN=64, BK=16, 16x16 threads, 4x4 per thread. All dims divide evenly
// for every call in this problem (M=2048; N in {2112,6144,8192,4096} all
// /64; K in {4096,1536,512,4096} all /16), so no bounds checks.
// ---------------------------------------------------------------------------
__global__ __launch_bounds__(256) void gemm_abt(
    const float* __restrict__ A, int lda,
    const float* __restrict__ B,
    float* __restrict__ C, int ldc,
    int M, int N, int K)
{
    __shared__ float As[64][17];   // +1 pad: breaks 4-way bank conflict
    __shared__ float Bs[64][17];

    const int tid = threadIdx.x;
    const int tx = tid & 15;       // 0..15 -> col group
    const int ty = tid >> 4;       // 0..15 -> row group
    const int m0 = blockIdx.y * 64;
    const int n0 = blockIdx.x * 64;

    float acc[4][4];
    #pragma unroll
    for (int i = 0; i < 4; ++i)
        #pragma unroll
        for (int j = 0; j < 4; ++j) acc[i][j] = 0.f;

    for (int k0 = 0; k0 < K; k0 += 16) {
        #pragma unroll
        for (int l = 0; l < 4; ++l) {
            int idx = l * 256 + tid;
            int r = idx >> 4, c = idx & 15;
            As[r][c] = A[(size_t)(m0 + r) * lda + k0 + c];
        }
        #pragma unroll
        for (int l = 0; l < 4; ++l) {
            int idx = l * 256 + tid;
            int r = idx >> 4, c = idx & 15;
            Bs[r][c] = B[(size_t)(n0 + r) * K + k0 + c];
        }
        __syncthreads();

        #pragma unroll
        for (int kk = 0; kk < 16; ++kk) {
            float a_[4], b_[4];
            #pragma unroll
            for (int i = 0; i < 4; ++i) a_[i] = As[ty * 4 + i][kk];
            #pragma unroll
            for (int j = 0; j < 4; ++j) b_[j] = Bs[tx * 4 + j][kk];
            #pragma unroll
            for (int i = 0; i < 4; ++i)
                #pragma unroll
                for (int j = 0; j < 4; ++j)
                    acc[i][j] += a_[i] * b_[j];
        }
        __syncthreads();
    }

    #pragma unroll
    for (int i = 0; i < 4; ++i)
        #pragma unroll
        for (int j = 0; j < 4; ++j)
            C[(size_t)(m0 + ty * 4 + i) * ldc + n0 + tx * 4 + j] = acc[i][j];
}

// ---------------------------------------------------------------------------
// Per-row (one block per sequence position): RMSNorm(cq), RMSNorm(ckv),
// RoPE on k_pe. All in-place on the fused activation buffer a (S, 2112).
// ---------------------------------------------------------------------------
__global__ __launch_bounds__(256) void norm_rope_kernel(
    float* __restrict__ a,
    const float* __restrict__ q_ln_w,
    const float* __restrict__ kv_ln_w,
    const int* __restrict__ pos_ids)
{
    const int s = blockIdx.x;
    float* row = a + (size_t)s * FUSED_N;
    __shared__ float red[256];
    const int tid = threadIdx.x;

    // --- cq: RMSNorm over first 1536 ---
    float ss = 0.f;
    for (int i = tid; i < Q_LORA; i += 256) { float v = row[i]; ss += v * v; }
    red[tid] = ss;
    __syncthreads();
    for (int w = 128; w > 0; w >>= 1) {
        if (tid < w) red[tid] += red[tid + w];
        __syncthreads();
    }
    float scale_q = rsqrtf(red[0] / (float)Q_LORA + 1e-6f);
    __syncthreads();
    for (int i = tid; i < Q_LORA; i += 256) row[i] = row[i] * scale_q * q_ln_w[i];
    __syncthreads();

    // --- ckv: RMSNorm over next 512 ---
    ss = 0.f;
    for (int i = tid; i < KV_LORA; i += 256) { float v = row[Q_LORA + i]; ss += v * v; }
    red[tid] = ss;
    __syncthreads();
    for (int w = 128; w > 0; w >>= 1) {
        if (tid < w) red[tid] += red[tid + w];
        __syncthreads();
    }
    float scale_kv = rsqrtf(red[0] / (float)KV_LORA + 1e-6f);
    __syncthreads();
    for (int i = tid; i < KV_LORA; i += 256) row[Q_LORA + i] = row[Q_LORA + i] * scale_kv * kv_ln_w[i];

    // --- k_pe RoPE (64 dims, half-split form) ---
    if (tid < 32) {
        const int j = tid;
        float pos = (float)pos_ids[s];
        // inv_freq = 10000^(-2j/64) = exp(-j * ln(10000)/32)
        float inv_freq = expf(-(float)j * (9.210340371976184f / 32.f));
        float ang = pos * inv_freq;
        float c = cosf(ang), sn = sinf(ang);
        float x1 = row[Q_LORA + KV_LORA + j];
        float x2 = row[Q_LORA + KV_LORA + 32 + j];
        row[Q_LORA + KV_LORA + j]      = x1 * c - x2 * sn;
        row[Q_LORA + KV_LORA + 32 + j] = x2 * c + x1 * sn;
    }
}

// ---------------------------------------------------------------------------
// RoPE on q_pe: q is (S*H, 192); rope dims are [128,192). One thread per
// (s,h) pair.
// ---------------------------------------------------------------------------
__global__ __launch_bounds__(256) void rope_q_kernel(
    float* __restrict__ q, const int* __restrict__ pos_ids)
{
    int idx = blockIdx.x * blockDim.x + threadIdx.x;
    if (idx >= S_LEN * NHEAD) return;
    int s = idx >> 5;  // / NHEAD
    float pos = (float)pos_ids[s];
    float* qp = q + (size_t)idx * QK_DIM + NOPE;
    #pragma unroll 4
    for (int j = 0; j < 32; ++j) {
        float inv_freq = expf(-(float)j * (9.210340371976184f / 32.f));
        float ang = pos * inv_freq;
        float c = cosf(ang), sn = sinf(ang);
        float x1 = qp[j], x2 = qp[32 + j];
        qp[j]      = x1 * c - x2 * sn;
        qp[32 + j] = x2 * c + x1 * sn;
    }
}

// ---------------------------------------------------------------------------
// Flash-style causal attention.
//   q:    (S, H, 192)  already roped
//   kv:   (S, H, 256)  [k_nope | v]
//   abuf: (S, 2112)    k_pe (roped) at offset 2048, shared across heads
//   attn: (S, H, 128)
// Q-tile = 32 rows, K-tile = 16. Block = 256 threads, grid = (S/32, H).
// Static LDS ~48 KB.
// ---------------------------------------------------------------------------
__global__ __launch_bounds__(256) void attn_kernel(
    const float* __restrict__ q,
    const float* __restrict__ kv,
    const float* __restrict__ abuf,
    float* __restrict__ attn)
{
    constexpr int QT = 32, KT = 16;
    __shared__ float qs[QT][194];
    __shared__ float ks[KT][194];
    __shared__ float vs[KT][130];
    __shared__ float ps[QT][KT + 1];
    __shared__ float mrow[QT], lrow[QT], arow[QT];

    const int q0 = blockIdx.x * QT;
    const int h = blockIdx.y;
    const int tid = threadIdx.x;
    const int r = tid >> 3;   // 0..31 : q row within tile
    const int cg = tid & 7;   // 0..7  : col group

    float O[16];
    #pragma unroll
    for (int j = 0; j < 16; ++j) O[j] = 0.f;

    // load Q tile
    for (int idx = tid; idx < QT * QK_DIM; idx += 256) {
        int rr = idx / QK_DIM, d = idx - rr * QK_DIM;
        qs[rr][d] = q[((size_t)(q0 + rr) * NHEAD + h) * QK_DIM + d];
    }
    if (tid < QT) { mrow[tid] = -1e30f; lrow[tid] = 0.f; }
    __syncthreads();

    const float scale = 0.07216878364870323f; // 1/sqrt(192)
    const int ntile = q0 / KT + 2;            // covers t <= q0+31

    for (int tt = 0; tt < ntile; ++tt) {
        const int t0 = tt * KT;
        // load K/V tile
        for (int idx = tid; idx < KT * 128; idx += 256) {
            int rr = idx >> 7, d = idx & 127;
            size_t base = ((size_t)(t0 + rr) * NHEAD + h) * 256;
            ks[rr][d] = kv[base + d];
            vs[rr][d] = kv[base + 128 + d];
        }
        for (int idx = tid; idx < KT * 64; idx += 256) {
            int rr = idx >> 6, d = idx & 63;
            ks[rr][128 + d] = abuf[(size_t)(t0 + rr) * FUSED_N + 2048 + d];
        }
        __syncthreads();

        // scores: each thread does row r, cols cg and cg+8
        float s0 = 0.f, s1 = 0.f;
        #pragma unroll 4
        for (int d = 0; d < QK_DIM; ++d) {
            float qd = qs[r][d];
            s0 += qd * ks[cg][d];
            s1 += qd * ks[cg + 8][d];
        }
        s0 *= scale; s1 *= scale;
        if (t0 + cg > q0 + r)     s0 = -1e30f;
        if (t0 + cg + 8 > q0 + r) s1 = -1e30f;
        ps[r][cg]     = s0;
        ps[r][cg + 8] = s1;
        __syncthreads();

        // online softmax bookkeeping: thread t handles row t
        if (tid < QT) {
            float mold = mrow[tid];
            float mx = mold;
            #pragma unroll
            for (int c = 0; c < KT; ++c) mx = fmaxf(mx, ps[tid][c]);
            float al = __expf(mold - mx);
            float ls = 0.f;
            #pragma unroll
            for (int c = 0; c < KT; ++c) {
                float p = __expf(ps[tid][c] - mx);
                ps[tid][c] = p;
                ls += p;
            }
            mrow[tid] = mx;
            lrow[tid] = lrow[tid] * al + ls;
            arow[tid] = al;
        }
        __syncthreads();

        // O update: cols cg + 8*j (consecutive within lane group: no bank conflict)
        float al = arow[r];
        #pragma unroll
        for (int j = 0; j < 16; ++j) O[j] *= al;
        #pragma unroll 4
        for (int t = 0; t < KT; ++t) {
            float p = ps[r][t];
            #pragma unroll
            for (int j = 0; j < 16; ++j) O[j] += p * vs[t][cg + 8 * j];
        }
        __syncthreads();
    }

    float linv = 1.f / lrow[r];
    #pragma unroll
    for (int j = 0; j < 16; ++j)
        attn[((size_t)(q0 + r) * NHEAD + h) * VDIM + cg + 8 * j] = O[j] * linv;
}

// ---------------------------------------------------------------------------
extern "C" void kernel_launch(void* const* d_in, const int* in_sizes, int n_in,
                              void* d_out, int out_size, void* d_ws, size_t ws_size,
                              hipStream_t stream)
{
    const int*   pos    = (const int*)d_in[0];
    const float* hs     = (const float*)d_in[1];
    const float* w_a    = (const float*)d_in[2];
    const float* qlnw   = (const float*)d_in[3];
    const float* kvlnw  = (const float*)d_in[4];
    const float* w_qb   = (const float*)d_in[5];
    const float* w_kvb  = (const float*)d_in[6];
    const float* w_o    = (const float*)d_in[7];
    float* out = (float*)d_out;

    float* ws       = (float*)d_ws;
    float* a_buf    = ws;                                    // (2048, 2112)
    float* q_buf    = a_buf  + (size_t)S_LEN * FUSED_N;      // (2048, 32, 192)
    float* kv_buf   = q_buf  + (size_t)S_LEN * NHEAD * QK_DIM;   // (2048, 32, 256)
    float* attn_buf = kv_buf + (size_t)S_LEN * NHEAD * 256;  // (2048, 32, 128)

    dim3 blk(256);

    // 1. a = hs @ w_fused_a^T : (2048, 2112), K=4096
    gemm_abt<<<dim3(FUSED_N / 64, S_LEN / 64), blk, 0, stream>>>(
        hs, HID, w_a, a_buf, FUSED_N, S_LEN, FUSED_N, HID);

    // 2. RMSNorm cq / ckv + k_pe RoPE (in place)
    norm_rope_kernel<<<S_LEN, 256, 0, stream>>>(a_buf, qlnw, kvlnw, pos);

    // 3. q = cq @ w_q_b^T : (2048, 6144), K=1536  (A has row stride 2112)
    gemm_abt<<<dim3(NHEAD * QK_DIM / 64, S_LEN / 64), blk, 0, stream>>>(
        a_buf, FUSED_N, w_qb, q_buf, NHEAD * QK_DIM, S_LEN, NHEAD * QK_DIM, Q_LORA);

    // 4. kv = ckv @ w_kv_b^T : (2048, 8192), K=512
    gemm_abt<<<dim3(NHEAD * 256 / 64, S_LEN / 64), blk, 0, stream>>>(
        a_buf + Q_LORA, FUSED_N, w_kvb, kv_buf, NHEAD * 256, S_LEN, NHEAD * 256, KV_LORA);

    // 5. RoPE on q_pe
    rope_q_kernel<<<(S_LEN * NHEAD + 255) / 256, 256, 0, stream>>>(q_buf, pos);

    // 6. causal flash attention -> attn (2048, 32, 128)
    attn_kernel<<<dim3(S_LEN / 32, NHEAD), blk, 0, stream>>>(
        q_buf, kv_buf, a_buf, attn_buf);

    // 7. out = attn @ w_o^T : (2048, 4096), K=4096
    gemm_abt<<<dim3(HID / 64, S_LEN / 64), blk, 0, stream>>>(
        attn_buf, NHEAD * VDIM, w_o, out, HID, S_LEN, HID, NHEAD * VDIM);
}

// Round 2
// 3848.325 us; speedup vs baseline: 1.7624x; 1.7624x over previous
//
#include <hip/hip_runtime.h>
#include <cmath>

// Problem constants
#define S_LEN 2048
#define HID 4096
#define NHEAD 32
#define Q_LORA 1536
#define KV_LORA 512
#define NOPE 128
#define ROPE_D 64
#define VDIM 128
#define QK_DIM 192       // NOPE + ROPE
#define FUSED_N 2112     // Q_LORA + KV_LORA + ROPE

typedef __attribute__((ext_vector_type(8))) short short8;
typedef __attribute__((ext_vector_type(4))) float floatx4;

// float -> bf16 bits, round-to-nearest-even
__device__ inline short f2bf(float f) {
    union { float f; unsigned u; } v; v.f = f;
    unsigned r = (v.u + 0x7fffu + ((v.u >> 16) & 1u)) >> 16;
    return (short)r;
}

// ---------------------------------------------------------------------------
// Generic tiled fp32 GEMM:  C(M,N) = A(M,K; lda) * B(N,K; ldb=K)^T
// (unchanged from round 0 — verified correct)
// ---------------------------------------------------------------------------
__global__ __launch_bounds__(256) void gemm_abt(
    const float* __restrict__ A, int lda,
    const float* __restrict__ B,
    float* __restrict__ C, int ldc,
    int M, int N, int K)
{
    __shared__ float As[64][17];
    __shared__ float Bs[64][17];

    const int tid = threadIdx.x;
    const int tx = tid & 15;
    const int ty = tid >> 4;
    const int m0 = blockIdx.y * 64;
    const int n0 = blockIdx.x * 64;

    float acc[4][4];
    #pragma unroll
    for (int i = 0; i < 4; ++i)
        #pragma unroll
        for (int j = 0; j < 4; ++j) acc[i][j] = 0.f;

    for (int k0 = 0; k0 < K; k0 += 16) {
        #pragma unroll
        for (int l = 0; l < 4; ++l) {
            int idx = l * 256 + tid;
            int r = idx >> 4, c = idx & 15;
            As[r][c] = A[(size_t)(m0 + r) * lda + k0 + c];
        }
        #pragma unroll
        for (int l = 0; l < 4; ++l) {
            int idx = l * 256 + tid;
            int r = idx >> 4, c = idx & 15;
            Bs[r][c] = B[(size_t)(n0 + r) * K + k0 + c];
        }
        __syncthreads();

        #pragma unroll
        for (int kk = 0; kk < 16; ++kk) {
            float a_[4], b_[4];
            #pragma unroll
            for (int i = 0; i < 4; ++i) a_[i] = As[ty * 4 + i][kk];
            #pragma unroll
            for (int j = 0; j < 4; ++j) b_[j] = Bs[tx * 4 + j][kk];
            #pragma unroll
            for (int i = 0; i < 4; ++i)
                #pragma unroll
                for (int j = 0; j < 4; ++j)
                    acc[i][j] += a_[i] * b_[j];
        }
        __syncthreads();
    }

    #pragma unroll
    for (int i = 0; i < 4; ++i)
        #pragma unroll
        for (int j = 0; j < 4; ++j)
            C[(size_t)(m0 + ty * 4 + i) * ldc + n0 + tx * 4 + j] = acc[i][j];
}

// ---------------------------------------------------------------------------
// RMSNorm(cq), RMSNorm(ckv), RoPE on k_pe — in place on a (S, 2112).
// (unchanged, verified)
// ---------------------------------------------------------------------------
__global__ __launch_bounds__(256) void norm_rope_kernel(
    float* __restrict__ a,
    const float* __restrict__ q_ln_w,
    const float* __restrict__ kv_ln_w,
    const int* __restrict__ pos_ids)
{
    const int s = blockIdx.x;
    float* row = a + (size_t)s * FUSED_N;
    __shared__ float red[256];
    const int tid = threadIdx.x;

    float ss = 0.f;
    for (int i = tid; i < Q_LORA; i += 256) { float v = row[i]; ss += v * v; }
    red[tid] = ss;
    __syncthreads();
    for (int w = 128; w > 0; w >>= 1) {
        if (tid < w) red[tid] += red[tid + w];
        __syncthreads();
    }
    float scale_q = rsqrtf(red[0] / (float)Q_LORA + 1e-6f);
    __syncthreads();
    for (int i = tid; i < Q_LORA; i += 256) row[i] = row[i] * scale_q * q_ln_w[i];
    __syncthreads();

    ss = 0.f;
    for (int i = tid; i < KV_LORA; i += 256) { float v = row[Q_LORA + i]; ss += v * v; }
    red[tid] = ss;
    __syncthreads();
    for (int w = 128; w > 0; w >>= 1) {
        if (tid < w) red[tid] += red[tid + w];
        __syncthreads();
    }
    float scale_kv = rsqrtf(red[0] / (float)KV_LORA + 1e-6f);
    __syncthreads();
    for (int i = tid; i < KV_LORA; i += 256) row[Q_LORA + i] = row[Q_LORA + i] * scale_kv * kv_ln_w[i];

    if (tid < 32) {
        const int j = tid;
        float pos = (float)pos_ids[s];
        float inv_freq = expf(-(float)j * (9.210340371976184f / 32.f));
        float ang = pos * inv_freq;
        float c = cosf(ang), sn = sinf(ang);
        float x1 = row[Q_LORA + KV_LORA + j];
        float x2 = row[Q_LORA + KV_LORA + 32 + j];
        row[Q_LORA + KV_LORA + j]      = x1 * c - x2 * sn;
        row[Q_LORA + KV_LORA + 32 + j] = x2 * c + x1 * sn;
    }
}

// ---------------------------------------------------------------------------
// RoPE on q_pe (unchanged, verified)
// ---------------------------------------------------------------------------
__global__ __launch_bounds__(256) void rope_q_kernel(
    float* __restrict__ q, const int* __restrict__ pos_ids)
{
    int idx = blockIdx.x * blockDim.x + threadIdx.x;
    if (idx >= S_LEN * NHEAD) return;
    int s = idx >> 5;
    float pos = (float)pos_ids[s];
    float* qp = q + (size_t)idx * QK_DIM + NOPE;
    #pragma unroll 4
    for (int j = 0; j < 32; ++j) {
        float inv_freq = expf(-(float)j * (9.210340371976184f / 32.f));
        float ang = pos * inv_freq;
        float c = cosf(ang), sn = sinf(ang);
        float x1 = qp[j], x2 = qp[32 + j];
        qp[j]      = x1 * c - x2 * sn;
        qp[32 + j] = x2 * c + x1 * sn;
    }
}

// ---------------------------------------------------------------------------
// MFMA bf16 flash attention (causal).
//   q:    (S, H, 192) fp32, roped
//   kv:   (S, H, 256) fp32  [k_nope | v]
//   abuf: (S, 2112)   fp32, k_pe (roped) at offset 2048, shared across heads
//   attn: (S, H, 128) fp32
// Block = 256 thr = 4 waves; wave w owns Q rows [q0+16w, q0+16w+16).
// K-tile = 32. mfma_f32_16x16x32_bf16:
//   A[m=lane&15][k=(lane>>4)*8+j]; B[k=(lane>>4)*8+j][n=lane&15];
//   C/D: col=lane&15, row=(lane>>4)*4+reg.
// LDS layouts are 16B fragment blocks ordered so frag reads are b128 with
// <=2-way bank aliasing (free per m136):
//   KF[c:6][quad:4][key:32]   (K incl. k_pe, bf16)
//   VF[kq:4][vcol:128]        (V transposed, 8 keys per block)
//   PA[wave:4][kq:4][m:16]    (P in A-layout)
// ---------------------------------------------------------------------------
__global__ __launch_bounds__(256) void attn_mfma(
    const float* __restrict__ q,
    const float* __restrict__ kv,
    const float* __restrict__ abuf,
    float* __restrict__ attn)
{
    __shared__ short8 KF[768];
    __shared__ short8 VF[512];
    __shared__ short8 PA[256];

    const int tid  = threadIdx.x;
    const int wave = tid >> 6;
    const int lane = tid & 63;
    const int m    = lane & 15;
    const int quad = lane >> 4;
    const int h    = blockIdx.y;
    const int q0   = blockIdx.x * 64;
    const int qrow_base = q0 + wave * 16;

    // Q fragments (6 chunks of 16x32), held in registers for the whole block
    short8 qf[6];
    {
        const float* qrow = q + ((size_t)(qrow_base + m) * NHEAD + h) * QK_DIM;
        #pragma unroll
        for (int c = 0; c < 6; ++c) {
            const float* p = qrow + c * 32 + quad * 8;
            short8 v;
            #pragma unroll
            for (int j = 0; j < 8; ++j) v[j] = f2bf(p[j]);
            qf[c] = v;
        }
    }

    floatx4 O[8];
    #pragma unroll
    for (int t = 0; t < 8; ++t) O[t] = (floatx4){0.f, 0.f, 0.f, 0.f};
    float mrow[4] = {-1e30f, -1e30f, -1e30f, -1e30f};
    float lrow[4] = {0.f, 0.f, 0.f, 0.f};

    const float scale = 0.07216878364870323f; // 1/sqrt(192)
    const int ntile = (q0 + 64) / 32;         // covers keys <= q0+63
    short* pas = (short*)PA;

    for (int tt = 0; tt < ntile; ++tt) {
        const int t0 = tt * 32;
        __syncthreads();   // protect previous tile's LDS

        // ---- stage K (k_nope: chunks 0..3) ----
        #pragma unroll
        for (int rep = 0; rep < 2; ++rep) {
            int i = rep * 256 + tid;
            int key = i >> 4, cq = i & 15, c = cq >> 2, qd = cq & 3;
            const float* src = kv + ((size_t)(t0 + key) * NHEAD + h) * 256 + c * 32 + qd * 8;
            short8 v;
            #pragma unroll
            for (int j = 0; j < 8; ++j) v[j] = f2bf(src[j]);
            KF[c * 128 + qd * 32 + key] = v;
        }
        // ---- stage k_pe (chunks 4,5), shared across heads ----
        {
            int key = tid >> 3, cq = tid & 7, c = cq >> 2, qd = cq & 3;
            const float* src = abuf + (size_t)(t0 + key) * FUSED_N + 2048 + c * 32 + qd * 8;
            short8 v;
            #pragma unroll
            for (int j = 0; j < 8; ++j) v[j] = f2bf(src[j]);
            KF[(c + 4) * 128 + qd * 32 + key] = v;
        }
        // ---- stage V transposed: VF[kq][vcol] holds keys kq*8..kq*8+7 ----
        #pragma unroll
        for (int rep = 0; rep < 2; ++rep) {
            int i = rep * 256 + tid;
            int kq = i >> 7, vc = i & 127;
            short8 v;
            #pragma unroll
            for (int j = 0; j < 8; ++j)
                v[j] = f2bf(kv[((size_t)(t0 + kq * 8 + j) * NHEAD + h) * 256 + 128 + vc]);
            VF[kq * 128 + vc] = v;
        }
        __syncthreads();

        // ---- QK^T: two 16x16 key tiles ----
        floatx4 s0 = (floatx4){0.f, 0.f, 0.f, 0.f};
        floatx4 s1 = (floatx4){0.f, 0.f, 0.f, 0.f};
        const int kb = quad * 32 + m;
        #pragma unroll
        for (int c = 0; c < 6; ++c) {
            s0 = __builtin_amdgcn_mfma_f32_16x16x32_bf16(qf[c], KF[c * 128 + kb],      s0, 0, 0, 0);
            s1 = __builtin_amdgcn_mfma_f32_16x16x32_bf16(qf[c], KF[c * 128 + kb + 16], s1, 0, 0, 0);
        }

        // ---- mask + online softmax (C layout: row = quad*4+reg, col = m) ----
        const int qb = qrow_base + quad * 4;
        float sv0[4], sv1[4];
        #pragma unroll
        for (int r = 0; r < 4; ++r) {
            float a0 = s0[r] * scale;
            float a1 = s1[r] * scale;
            if (t0 + m > qb + r)      a0 = -1e30f;
            if (t0 + 16 + m > qb + r) a1 = -1e30f;
            sv0[r] = a0; sv1[r] = a1;
        }
        #pragma unroll
        for (int r = 0; r < 4; ++r) {
            float v = fmaxf(sv0[r], sv1[r]);
            v = fmaxf(v, __shfl_xor(v, 1));
            v = fmaxf(v, __shfl_xor(v, 2));
            v = fmaxf(v, __shfl_xor(v, 4));
            v = fmaxf(v, __shfl_xor(v, 8));
            float mnew  = fmaxf(mrow[r], v);
            float alpha = __expf(mrow[r] - mnew);
            float p0 = __expf(sv0[r] - mnew);
            float p1 = __expf(sv1[r] - mnew);
            float rs = p0 + p1;
            rs += __shfl_xor(rs, 1);
            rs += __shfl_xor(rs, 2);
            rs += __shfl_xor(rs, 4);
            rs += __shfl_xor(rs, 8);
            lrow[r] = lrow[r] * alpha + rs;
            mrow[r] = mnew;
            #pragma unroll
            for (int t = 0; t < 8; ++t) {
                O[t][r] *= alpha;
            }
            // write P to per-wave A-layout region: key = col(+16), kq = key>>3
            int row = quad * 4 + r;
            short* pw = pas + wave * 512;
            pw[((m >> 3) + 0) * 128 + row * 8 + (m & 7)] = f2bf(p0);
            pw[((m >> 3) + 2) * 128 + row * 8 + (m & 7)] = f2bf(p1);
        }

        // ---- PV: O[16x128] += P(16x32) * V(32x128) ----
        short8 pfrag = PA[wave * 64 + quad * 16 + m];
        #pragma unroll
        for (int t = 0; t < 8; ++t) {
            O[t] = __builtin_amdgcn_mfma_f32_16x16x32_bf16(
                pfrag, VF[quad * 128 + m + 16 * t], O[t], 0, 0, 0);
        }
    }

    // ---- epilogue: divide by l, store ----
    #pragma unroll
    for (int r = 0; r < 4; ++r) {
        float linv = 1.f / lrow[r];
        int row = qrow_base + quad * 4 + r;
        float* dst = attn + ((size_t)row * NHEAD + h) * VDIM + m;
        #pragma unroll
        for (int t = 0; t < 8; ++t)
            dst[16 * t] = O[t][r] * linv;
    }
}

// ---------------------------------------------------------------------------
extern "C" void kernel_launch(void* const* d_in, const int* in_sizes, int n_in,
                              void* d_out, int out_size, void* d_ws, size_t ws_size,
                              hipStream_t stream)
{
    const int*   pos    = (const int*)d_in[0];
    const float* hs     = (const float*)d_in[1];
    const float* w_a    = (const float*)d_in[2];
    const float* qlnw   = (const float*)d_in[3];
    const float* kvlnw  = (const float*)d_in[4];
    const float* w_qb   = (const float*)d_in[5];
    const float* w_kvb  = (const float*)d_in[6];
    const float* w_o    = (const float*)d_in[7];
    float* out = (float*)d_out;

    float* ws       = (float*)d_ws;
    float* a_buf    = ws;                                        // (2048, 2112)
    float* q_buf    = a_buf  + (size_t)S_LEN * FUSED_N;          // (2048, 32, 192)
    float* kv_buf   = q_buf  + (size_t)S_LEN * NHEAD * QK_DIM;   // (2048, 32, 256)
    float* attn_buf = kv_buf + (size_t)S_LEN * NHEAD * 256;      // (2048, 32, 128)

    dim3 blk(256);

    // 1. a = hs @ w_fused_a^T : (2048, 2112), K=4096
    gemm_abt<<<dim3(FUSED_N / 64, S_LEN / 64), blk, 0, stream>>>(
        hs, HID, w_a, a_buf, FUSED_N, S_LEN, FUSED_N, HID);

    // 2. RMSNorm cq / ckv + k_pe RoPE (in place)
    norm_rope_kernel<<<S_LEN, 256, 0, stream>>>(a_buf, qlnw, kvlnw, pos);

    // 3. q = cq @ w_q_b^T : (2048, 6144), K=1536
    gemm_abt<<<dim3(NHEAD * QK_DIM / 64, S_LEN / 64), blk, 0, stream>>>(
        a_buf, FUSED_N, w_qb, q_buf, NHEAD * QK_DIM, S_LEN, NHEAD * QK_DIM, Q_LORA);

    // 4. kv = ckv @ w_kv_b^T : (2048, 8192), K=512
    gemm_abt<<<dim3(NHEAD * 256 / 64, S_LEN / 64), blk, 0, stream>>>(
        a_buf + Q_LORA, FUSED_N, w_kvb, kv_buf, NHEAD * 256, S_LEN, NHEAD * 256, KV_LORA);

    // 5. RoPE on q_pe
    rope_q_kernel<<<(S_LEN * NHEAD + 255) / 256, 256, 0, stream>>>(q_buf, pos);

    // 6. MFMA flash attention -> attn (2048, 32, 128)
    attn_mfma<<<dim3(S_LEN / 64, NHEAD), blk, 0, stream>>>(
        q_buf, kv_buf, a_buf, attn_buf);

    // 7. out = attn @ w_o^T : (2048, 4096), K=4096
    gemm_abt<<<dim3(HID / 64, S_LEN / 64), blk, 0, stream>>>(
        attn_buf, NHEAD * VDIM, w_o, out, HID, S_LEN, HID, NHEAD * VDIM);
}

// Round 4
// 922.932 us; speedup vs baseline: 7.3487x; 4.1697x over previous
//
#include <hip/hip_runtime.h>
#include <cmath>

// Problem constants
#define S_LEN 2048
#define HID 4096
#define NHEAD 32
#define Q_LORA 1536
#define KV_LORA 512
#define NOPE 128
#define ROPE_D 64
#define VDIM 128
#define QK_DIM 192       // NOPE + ROPE
#define FUSED_N 2112     // Q_LORA + KV_LORA + ROPE
#define FUSED_NPAD 2176  // padded to a multiple of 128

typedef __attribute__((ext_vector_type(8))) short short8;
typedef __attribute__((ext_vector_type(4))) float floatx4;
typedef unsigned short ushort_t;

// float -> bf16 bits, round-to-nearest-even
__device__ inline short f2bf(float f) {
    union { float f; unsigned u; } v; v.f = f;
    unsigned r = (v.u + 0x7fffu + ((v.u >> 16) & 1u)) >> 16;
    return (short)r;
}
__device__ inline float bf2f(ushort_t u) {
    union { unsigned u; float f; } v; v.u = ((unsigned)u) << 16; return v.f;
}

// async 16B global -> LDS (LDS dest: wave-uniform base + lane*16)
#define GLOAD16(g, l)                                                        \
    __builtin_amdgcn_global_load_lds(                                        \
        (const __attribute__((address_space(1))) unsigned int*)(g),          \
        (__attribute__((address_space(3))) unsigned int*)(l), 16, 0, 0)

// ---------------------------------------------------------------------------
// fp32 -> bf16 converters (n % 8 == 0)
// ---------------------------------------------------------------------------
__global__ __launch_bounds__(256) void conv_bf16(
    const float* __restrict__ src, ushort_t* __restrict__ dst, int n)
{
    int i = (blockIdx.x * 256 + threadIdx.x) * 8;
    if (i >= n) return;
    const float4* s = (const float4*)(src + i);
    float4 a = s[0], b = s[1];
    short8 v;
    v[0] = f2bf(a.x); v[1] = f2bf(a.y); v[2] = f2bf(a.z); v[3] = f2bf(a.w);
    v[4] = f2bf(b.x); v[5] = f2bf(b.y); v[6] = f2bf(b.z); v[7] = f2bf(b.w);
    *(short8*)(dst + i) = v;
}

__global__ __launch_bounds__(256) void conv_bf16_pad(
    const float* __restrict__ src, ushort_t* __restrict__ dst, int n_src, int n_tot)
{
    int i = (blockIdx.x * 256 + threadIdx.x) * 8;
    if (i >= n_tot) return;
    short8 v;
    if (i < n_src) {
        const float4* s = (const float4*)(src + i);
        float4 a = s[0], b = s[1];
        v[0] = f2bf(a.x); v[1] = f2bf(a.y); v[2] = f2bf(a.z); v[3] = f2bf(a.w);
        v[4] = f2bf(b.x); v[5] = f2bf(b.y); v[6] = f2bf(b.z); v[7] = f2bf(b.w);
    } else {
        v = (short8){0,0,0,0,0,0,0,0};
    }
    *(short8*)(dst + i) = v;
}

// ---------------------------------------------------------------------------
// bf16 MFMA GEMM (m97 structure): C(M,N) = A(M,K) * B(N,K)^T
// 128x128 tile, BK=32, 4 waves in 2x2, each 64x64 via 4x4 mfma_16x16x32_bf16.
// LDS: fragment-order 16B blocks [rowblock:8][quad:4][lane:16].
// CT = float (fp32 out) or ushort_t (bf16 out). Store guard col < N.
// ---------------------------------------------------------------------------
__device__ inline void store_c(float* p, float v)    { *p = v; }
__device__ inline void store_c(ushort_t* p, float v) { *p = (ushort_t)f2bf(v); }

template <typename CT>
__global__ __launch_bounds__(256) void gemm_bf16(
    const ushort_t* __restrict__ A, int lda,
    const ushort_t* __restrict__ B, int ldb,
    CT* __restrict__ C, int ldc, int N, int K)
{
    __shared__ short8 As8[512];   // 8 KB
    __shared__ short8 Bs8[512];   // 8 KB

    const int tid  = threadIdx.x;
    const int lane = tid & 63;
    const int wave = tid >> 6;
    const int m    = lane & 15;
    const int quad = lane >> 4;
    const int wr   = wave >> 1, wc = wave & 1;
    const int m0 = blockIdx.y * 128;
    const int n0 = blockIdx.x * 128;

    floatx4 acc[4][4];
    #pragma unroll
    for (int i = 0; i < 4; ++i)
        #pragma unroll
        for (int j = 0; j < 4; ++j) acc[i][j] = (floatx4){0.f, 0.f, 0.f, 0.f};

    const int R0 = tid >> 6, q0s = (tid >> 4) & 3, e0 = tid & 15;
    const int R1 = (tid + 256) >> 6, q1s = ((tid + 256) >> 4) & 3, e1 = (tid + 256) & 15;

    for (int k0 = 0; k0 < K; k0 += 32) {
        __syncthreads();
        GLOAD16(A + (size_t)(m0 + R0 * 16 + e0) * lda + k0 + q0s * 8, &As8[tid]);
        GLOAD16(A + (size_t)(m0 + R1 * 16 + e1) * lda + k0 + q1s * 8, &As8[tid + 256]);
        GLOAD16(B + (size_t)(n0 + R0 * 16 + e0) * ldb + k0 + q0s * 8, &Bs8[tid]);
        GLOAD16(B + (size_t)(n0 + R1 * 16 + e1) * ldb + k0 + q1s * 8, &Bs8[tid + 256]);
        __syncthreads();

        short8 af[4], bfr[4];
        #pragma unroll
        for (int i = 0; i < 4; ++i) af[i]  = As8[((wr * 4 + i) * 4 + quad) * 16 + m];
        #pragma unroll
        for (int i = 0; i < 4; ++i) bfr[i] = Bs8[((wc * 4 + i) * 4 + quad) * 16 + m];

        #pragma unroll
        for (int ri = 0; ri < 4; ++ri)
            #pragma unroll
            for (int ci = 0; ci < 4; ++ci)
                acc[ri][ci] = __builtin_amdgcn_mfma_f32_16x16x32_bf16(
                    af[ri], bfr[ci], acc[ri][ci], 0, 0, 0);
    }

    #pragma unroll
    for (int ci = 0; ci < 4; ++ci) {
        int col = n0 + wc * 64 + ci * 16 + m;
        if (col < N) {
            #pragma unroll
            for (int ri = 0; ri < 4; ++ri) {
                int row = m0 + wr * 64 + ri * 16 + quad * 4;
                #pragma unroll
                for (int r = 0; r < 4; ++r)
                    store_c(&C[(size_t)(row + r) * ldc + col], acc[ri][ci][r]);
            }
        }
    }
}

// ---------------------------------------------------------------------------
// RMSNorm(cq), RMSNorm(ckv), RoPE on k_pe — in place on bf16 a (S, 2112).
// ---------------------------------------------------------------------------
__global__ __launch_bounds__(256) void norm_rope_kernel(
    ushort_t* __restrict__ a,
    const float* __restrict__ q_ln_w,
    const float* __restrict__ kv_ln_w,
    const int* __restrict__ pos_ids)
{
    const int s = blockIdx.x;
    ushort_t* row = a + (size_t)s * FUSED_N;
    __shared__ float red[256];
    const int tid = threadIdx.x;

    float ss = 0.f;
    for (int i = tid; i < Q_LORA; i += 256) { float v = bf2f(row[i]); ss += v * v; }
    red[tid] = ss;
    __syncthreads();
    for (int w = 128; w > 0; w >>= 1) {
        if (tid < w) red[tid] += red[tid + w];
        __syncthreads();
    }
    float scale_q = rsqrtf(red[0] / (float)Q_LORA + 1e-6f);
    __syncthreads();
    for (int i = tid; i < Q_LORA; i += 256)
        row[i] = (ushort_t)f2bf(bf2f(row[i]) * scale_q * q_ln_w[i]);
    __syncthreads();

    ss = 0.f;
    for (int i = tid; i < KV_LORA; i += 256) { float v = bf2f(row[Q_LORA + i]); ss += v * v; }
    red[tid] = ss;
    __syncthreads();
    for (int w = 128; w > 0; w >>= 1) {
        if (tid < w) red[tid] += red[tid + w];
        __syncthreads();
    }
    float scale_kv = rsqrtf(red[0] / (float)KV_LORA + 1e-6f);
    __syncthreads();
    for (int i = tid; i < KV_LORA; i += 256)
        row[Q_LORA + i] = (ushort_t)f2bf(bf2f(row[Q_LORA + i]) * scale_kv * kv_ln_w[i]);

    if (tid < 32) {
        const int j = tid;
        float pos = (float)pos_ids[s];
        float inv_freq = expf(-(float)j * (9.210340371976184f / 32.f));
        float ang = pos * inv_freq;
        float c = cosf(ang), sn = sinf(ang);
        float x1 = bf2f(row[Q_LORA + KV_LORA + j]);
        float x2 = bf2f(row[Q_LORA + KV_LORA + 32 + j]);
        row[Q_LORA + KV_LORA + j]      = (ushort_t)f2bf(x1 * c - x2 * sn);
        row[Q_LORA + KV_LORA + 32 + j] = (ushort_t)f2bf(x2 * c + x1 * sn);
    }
}

// ---------------------------------------------------------------------------
// RoPE on q_pe (bf16 in place): q is (S*H, 192), rope dims [128,192)
// ---------------------------------------------------------------------------
__global__ __launch_bounds__(256) void rope_q_kernel(
    ushort_t* __restrict__ q, const int* __restrict__ pos_ids)
{
    int idx = blockIdx.x * blockDim.x + threadIdx.x;
    if (idx >= S_LEN * NHEAD) return;
    int s = idx >> 5;
    float pos = (float)pos_ids[s];
    ushort_t* qp = q + (size_t)idx * QK_DIM + NOPE;
    #pragma unroll 4
    for (int j = 0; j < 32; ++j) {
        float inv_freq = expf(-(float)j * (9.210340371976184f / 32.f));
        float ang = pos * inv_freq;
        float c = cosf(ang), sn = sinf(ang);
        float x1 = bf2f(qp[j]), x2 = bf2f(qp[32 + j]);
        qp[j]      = (ushort_t)f2bf(x1 * c - x2 * sn);
        qp[32 + j] = (ushort_t)f2bf(x2 * c + x1 * sn);
    }
}

// ---------------------------------------------------------------------------
// MFMA bf16 flash attention (causal) — round-1-verified structure, now with
// native bf16 inputs/outputs (direct short8 loads, no convert).
//   q:    (S, H, 192) bf16, roped     kv: (S, H, 256) bf16 [k_nope | v]
//   abuf: (S, 2112) bf16, k_pe at 2048      attn: (S, H, 128) bf16
// ---------------------------------------------------------------------------
__global__ __launch_bounds__(256) void attn_mfma(
    const ushort_t* __restrict__ q,
    const ushort_t* __restrict__ kv,
    const ushort_t* __restrict__ abuf,
    ushort_t* __restrict__ attn)
{
    __shared__ short8 KF[768];
    __shared__ short8 VF[512];
    __shared__ short8 PA[256];

    const int tid  = threadIdx.x;
    const int wave = tid >> 6;
    const int lane = tid & 63;
    const int m    = lane & 15;
    const int quad = lane >> 4;
    const int h    = blockIdx.y;
    const int q0   = blockIdx.x * 64;
    const int qrow_base = q0 + wave * 16;

    short8 qf[6];
    {
        const ushort_t* qrow = q + ((size_t)(qrow_base + m) * NHEAD + h) * QK_DIM;
        #pragma unroll
        for (int c = 0; c < 6; ++c)
            qf[c] = *(const short8*)(qrow + c * 32 + quad * 8);
    }

    floatx4 O[8];
    #pragma unroll
    for (int t = 0; t < 8; ++t) O[t] = (floatx4){0.f, 0.f, 0.f, 0.f};
    float mrow[4] = {-1e30f, -1e30f, -1e30f, -1e30f};
    float lrow[4] = {0.f, 0.f, 0.f, 0.f};

    const float scale = 0.07216878364870323f; // 1/sqrt(192)
    const int ntile = (q0 + 64) / 32;
    short* pas = (short*)PA;

    for (int tt = 0; tt < ntile; ++tt) {
        const int t0 = tt * 32;
        __syncthreads();

        #pragma unroll
        for (int rep = 0; rep < 2; ++rep) {
            int i = rep * 256 + tid;
            int key = i >> 4, cq = i & 15, c = cq >> 2, qd = cq & 3;
            KF[c * 128 + qd * 32 + key] =
                *(const short8*)(kv + ((size_t)(t0 + key) * NHEAD + h) * 256 + c * 32 + qd * 8);
        }
        {
            int key = tid >> 3, cq = tid & 7, c = cq >> 2, qd = cq & 3;
            KF[(c + 4) * 128 + qd * 32 + key] =
                *(const short8*)(abuf + (size_t)(t0 + key) * FUSED_N + 2048 + c * 32 + qd * 8);
        }
        #pragma unroll
        for (int rep = 0; rep < 2; ++rep) {
            int i = rep * 256 + tid;
            int kq = i >> 7, vc = i & 127;
            short8 v;
            #pragma unroll
            for (int j = 0; j < 8; ++j)
                v[j] = (short)kv[((size_t)(t0 + kq * 8 + j) * NHEAD + h) * 256 + 128 + vc];
            VF[kq * 128 + vc] = v;
        }
        __syncthreads();

        floatx4 s0 = (floatx4){0.f, 0.f, 0.f, 0.f};
        floatx4 s1 = (floatx4){0.f, 0.f, 0.f, 0.f};
        const int kb = quad * 32 + m;
        #pragma unroll
        for (int c = 0; c < 6; ++c) {
            s0 = __builtin_amdgcn_mfma_f32_16x16x32_bf16(qf[c], KF[c * 128 + kb],      s0, 0, 0, 0);
            s1 = __builtin_amdgcn_mfma_f32_16x16x32_bf16(qf[c], KF[c * 128 + kb + 16], s1, 0, 0, 0);
        }

        const int qb = qrow_base + quad * 4;
        float sv0[4], sv1[4];
        #pragma unroll
        for (int r = 0; r < 4; ++r) {
            float a0 = s0[r] * scale;
            float a1 = s1[r] * scale;
            if (t0 + m > qb + r)      a0 = -1e30f;
            if (t0 + 16 + m > qb + r) a1 = -1e30f;
            sv0[r] = a0; sv1[r] = a1;
        }
        #pragma unroll
        for (int r = 0; r < 4; ++r) {
            float v = fmaxf(sv0[r], sv1[r]);
            v = fmaxf(v, __shfl_xor(v, 1));
            v = fmaxf(v, __shfl_xor(v, 2));
            v = fmaxf(v, __shfl_xor(v, 4));
            v = fmaxf(v, __shfl_xor(v, 8));
            float mnew  = fmaxf(mrow[r], v);
            float alpha = __expf(mrow[r] - mnew);
            float p0 = __expf(sv0[r] - mnew);
            float p1 = __expf(sv1[r] - mnew);
            float rs = p0 + p1;
            rs += __shfl_xor(rs, 1);
            rs += __shfl_xor(rs, 2);
            rs += __shfl_xor(rs, 4);
            rs += __shfl_xor(rs, 8);
            lrow[r] = lrow[r] * alpha + rs;
            mrow[r] = mnew;
            #pragma unroll
            for (int t = 0; t < 8; ++t) O[t][r] *= alpha;
            int row = quad * 4 + r;
            short* pw = pas + wave * 512;
            pw[((m >> 3) + 0) * 128 + row * 8 + (m & 7)] = f2bf(p0);
            pw[((m >> 3) + 2) * 128 + row * 8 + (m & 7)] = f2bf(p1);
        }

        short8 pfrag = PA[wave * 64 + quad * 16 + m];
        #pragma unroll
        for (int t = 0; t < 8; ++t) {
            O[t] = __builtin_amdgcn_mfma_f32_16x16x32_bf16(
                pfrag, VF[quad * 128 + m + 16 * t], O[t], 0, 0, 0);
        }
    }

    #pragma unroll
    for (int r = 0; r < 4; ++r) {
        float linv = 1.f / lrow[r];
        int row = qrow_base + quad * 4 + r;
        ushort_t* dst = attn + ((size_t)row * NHEAD + h) * VDIM + m;
        #pragma unroll
        for (int t = 0; t < 8; ++t)
            dst[16 * t] = (ushort_t)f2bf(O[t][r] * linv);
    }
}

// ---------------------------------------------------------------------------
extern "C" void kernel_launch(void* const* d_in, const int* in_sizes, int n_in,
                              void* d_out, int out_size, void* d_ws, size_t ws_size,
                              hipStream_t stream)
{
    const int*   pos    = (const int*)d_in[0];
    const float* hs     = (const float*)d_in[1];
    const float* w_a    = (const float*)d_in[2];
    const float* qlnw   = (const float*)d_in[3];
    const float* kvlnw  = (const float*)d_in[4];
    const float* w_qb   = (const float*)d_in[5];
    const float* w_kvb  = (const float*)d_in[6];
    const float* w_o    = (const float*)d_in[7];
    float* out = (float*)d_out;

    // workspace layout — all bf16, 146.0 MB total (round-3 crash was a
    // 272 MB layout overflowing d_ws; rounds 0-2 proved >=168 MB exists)
    char* p = (char*)d_ws;
    ushort_t* a_bf    = (ushort_t*)p; p += (size_t)S_LEN * FUSED_N * 2;          //  8.65 MB
    ushort_t* q_bf    = (ushort_t*)p; p += (size_t)S_LEN * NHEAD * QK_DIM * 2;   // 25.2 MB
    ushort_t* kv_bf   = (ushort_t*)p; p += (size_t)S_LEN * NHEAD * 256 * 2;      // 33.6 MB
    ushort_t* attn_bf = (ushort_t*)p; p += (size_t)S_LEN * HID * 2;              // 16.8 MB
    ushort_t* hs_bf   = (ushort_t*)p; p += (size_t)S_LEN * HID * 2;              // 16.8 MB
    ushort_t* w_a_bf  = (ushort_t*)p; p += (size_t)FUSED_NPAD * HID * 2;         // 17.8 MB
    ushort_t* w_qb_bf = (ushort_t*)p; p += (size_t)NHEAD * QK_DIM * Q_LORA * 2;  // 18.9 MB
    ushort_t* w_kvb_bf= (ushort_t*)p; p += (size_t)NHEAD * 256 * KV_LORA * 2;    //  8.4 MB
    // w_o_bf (33.6 MB) aliases hs_bf + w_a_bf (34.6 MB), both dead after gemm 1
    ushort_t* w_o_bf  = hs_bf;

    if (ws_size < (size_t)(p - (char*)d_ws)) return;  // fail loud, not fault

    dim3 blk(256);
    auto cgrid = [](size_t n) { return dim3((unsigned)((n / 8 + 255) / 256)); };

    // 0. fp32 -> bf16 (hs + weights for gemms 1,3,4)
    conv_bf16<<<cgrid((size_t)S_LEN * HID), blk, 0, stream>>>(hs, hs_bf, S_LEN * HID);
    conv_bf16_pad<<<cgrid((size_t)FUSED_NPAD * HID), blk, 0, stream>>>(
        w_a, w_a_bf, FUSED_N * HID, FUSED_NPAD * HID);
    conv_bf16<<<cgrid((size_t)NHEAD * QK_DIM * Q_LORA), blk, 0, stream>>>(
        w_qb, w_qb_bf, NHEAD * QK_DIM * Q_LORA);
    conv_bf16<<<cgrid((size_t)NHEAD * 256 * KV_LORA), blk, 0, stream>>>(
        w_kvb, w_kvb_bf, NHEAD * 256 * KV_LORA);

    // 1. a = hs @ w_fused_a^T : (2048, 2112) bf16, K=4096
    gemm_bf16<ushort_t><<<dim3(FUSED_NPAD / 128, S_LEN / 128), blk, 0, stream>>>(
        hs_bf, HID, w_a_bf, HID, a_bf, FUSED_N, FUSED_N, HID);

    // 1b. w_o -> bf16 (into region freed by gemm 1)
    conv_bf16<<<cgrid((size_t)HID * HID), blk, 0, stream>>>(w_o, w_o_bf, HID * HID);

    // 2. RMSNorm cq / ckv + k_pe RoPE (in place, bf16)
    norm_rope_kernel<<<S_LEN, 256, 0, stream>>>(a_bf, qlnw, kvlnw, pos);

    // 3. q = cq @ w_q_b^T : (2048, 6144) bf16, K=1536
    gemm_bf16<ushort_t><<<dim3(NHEAD * QK_DIM / 128, S_LEN / 128), blk, 0, stream>>>(
        a_bf, FUSED_N, w_qb_bf, Q_LORA, q_bf, NHEAD * QK_DIM, NHEAD * QK_DIM, Q_LORA);

    // 4. kv = ckv @ w_kv_b^T : (2048, 8192) bf16, K=512
    gemm_bf16<ushort_t><<<dim3(NHEAD * 256 / 128, S_LEN / 128), blk, 0, stream>>>(
        a_bf + Q_LORA, FUSED_N, w_kvb_bf, KV_LORA, kv_bf, NHEAD * 256, NHEAD * 256, KV_LORA);

    // 5. RoPE on q_pe (bf16 in place)
    rope_q_kernel<<<(S_LEN * NHEAD + 255) / 256, 256, 0, stream>>>(q_bf, pos);

    // 6. MFMA flash attention -> attn (2048, 32, 128) bf16
    attn_mfma<<<dim3(S_LEN / 64, NHEAD), blk, 0, stream>>>(
        q_bf, kv_bf, a_bf, attn_bf);

    // 7. out = attn @ w_o^T : (2048, 4096) fp32, K=4096
    gemm_bf16<float><<<dim3(HID / 128, S_LEN / 128), blk, 0, stream>>>(
        attn_bf, HID, w_o_bf, HID, out, HID, HID, HID);
}